// Round 9
// baseline (299.731 us; speedup 1.0000x reference)
//
#include <hip/hip_runtime.h>
#include <hip/hip_bf16.h>

// AttnBlock2D decoupled-GEMM pipeline, R9. B=4, C=512, N=4096 per batch.
//   kt[(b,i)][c] = (x.Wk + bk) * (log2e/sqrt(512))
//   qt[(b,j)][c] = x.Wq + bq
//   vc[c][(b,j)] = x.Wv + bv
//   P_h[b][i][jl] = exp2(kt.qt^T)   (unnormalized), Lpart row partials
//   otab[(b,i)][h*512+c] = P_h.V    (bf16 partial halves side by side)
//   out[b][co][n] = (Wo_dup . otab^T)(K=1024) * linv + bo
// R9: back to the PROVEN m97-class 128^2/BK=32 core (16KB LDS -> 4-5 blocks/CU,
// cross-block MFMA/LDS overlap, no lockstep barrier domain), keeping R5's
// XCD-aware 1D grids (FETCH-verified) and slim direct-store epilogues.

typedef __attribute__((ext_vector_type(4))) float f32x4;
typedef __attribute__((ext_vector_type(8))) short short8;
typedef __attribute__((ext_vector_type(4))) short short4v;

#define QSCALE 0.06376639774f   // (1/sqrt(512)) * log2(e)

__device__ __forceinline__ unsigned short f2bf(float f) {
  unsigned u = __builtin_bit_cast(unsigned, f);
  unsigned r = (u + 0x7FFFu + ((u >> 16) & 1u)) >> 16;   // RNE
  return (unsigned short)r;
}

__device__ __forceinline__ void gll16(const void* g, void* l) {
  __builtin_amdgcn_global_load_lds((const __attribute__((address_space(1))) void*)g,
                                   (__attribute__((address_space(3))) void*)l, 16, 0, 0);
}

#define MFMA_BF16(d, va, vb) \
  d = __builtin_amdgcn_mfma_f32_16x16x32_bf16(va, vb, d, 0, 0, 0)

// ==================== m97-class 128^2 core (4 waves, BK=32, 16KB LDS) ====================
// Verified R1-R3. Per K-tile: 2 gll16/thread, 8 ds_read_b128/wave, 16 MFMA/wave.
__device__ __forceinline__ void gemm_core(const short* __restrict__ A, int lda,
                                          const short* __restrict__ B, int ldb,
                                          int nk, short* lds, f32x4 (&acc)[4][4]) {
  const int tid = threadIdx.x, w = tid >> 6, lane = tid & 63;
  const int g = lane >> 4, l15 = lane & 15;
  const int wr = w >> 1, wc = w & 1;
  const int rsub = lane >> 2, slot = lane & 3;
  char* la = (char*)lds;
  char* lb = (char*)(lds + 128 * 32);
  for (int ki = 0; ki < nk; ++ki) {
    const int k0 = ki * 32;
    __syncthreads();
#pragma unroll
    for (int q = 0; q < 2; ++q) {
      int qq = w * 2 + q;
      int row = qq * 16 + rsub;
      int soff = ((slot ^ (row & 3)) * 16);
      gll16((const char*)(A + (size_t)row * lda + k0) + soff, la + qq * 1024);
      gll16((const char*)(B + (size_t)row * ldb + k0) + soff, lb + qq * 1024);
    }
    __syncthreads();
    short8 am[4], bn[4];
#pragma unroll
    for (int m = 0; m < 4; ++m) {
      int row = wr * 64 + m * 16 + l15;
      am[m] = *(const short8*)(la + row * 64 + ((g * 16) ^ ((l15 & 3) << 4)));
    }
#pragma unroll
    for (int n = 0; n < 4; ++n) {
      int row = wc * 64 + n * 16 + l15;
      bn[n] = *(const short8*)(lb + row * 64 + ((g * 16) ^ ((l15 & 3) << 4)));
    }
#pragma unroll
    for (int m = 0; m < 4; ++m)
#pragma unroll
      for (int n = 0; n < 4; ++n)
        MFMA_BF16(acc[m][n], am[m], bn[n]);
  }
}

// ---------------------------------------------------------------- cvt weights
__global__ __launch_bounds__(256) void cvt_w_kernel(
    const float* __restrict__ wk, const float* __restrict__ wq,
    const float* __restrict__ wv, const float* __restrict__ wo,
    short* __restrict__ o) {
  int z = blockIdx.y;
  const float* s = (z == 0) ? wk : (z == 1) ? wq : (z == 2) ? wv : wo;
  int i = blockIdx.x * 256 + threadIdx.x;
  float4 f = ((const float4*)s)[i];
  short4v v;
  v[0] = (short)f2bf(f.x); v[1] = (short)f2bf(f.y);
  v[2] = (short)f2bf(f.z); v[3] = (short)f2bf(f.w);
  if (z < 3) {
    *(short4v*)(o + z * 262144 + i * 4) = v;
  } else {                       // Wo duplicated along K: wdup[co][1024]
    int idx = i * 4, co = idx >> 9, cc = idx & 511;
    short* base = o + 786432 + co * 1024 + cc;
    *(short4v*)base = v;
    *(short4v*)(base + 512) = v;
  }
}

// --------------------------------------------------- transpose inp -> x_t bf16
__global__ __launch_bounds__(256) void transpose_x_kernel(
    const float* __restrict__ inp, short* __restrict__ xt) {
  __shared__ float t[32][33];
  int tx = threadIdx.x, ty = threadIdx.y;
  int n0 = blockIdx.x * 32, c0 = blockIdx.y * 32, b = blockIdx.z;
  const float* src = inp + ((size_t)(b * 512 + c0)) * 4096 + n0;
#pragma unroll
  for (int r = 0; r < 4; ++r) t[ty + r * 8][tx] = src[(ty + r * 8) * 4096 + tx];
  __syncthreads();
  short* dst = xt + ((size_t)((b << 12) + n0)) * 512 + c0;
#pragma unroll
  for (int r = 0; r < 4; ++r) dst[(ty + r * 8) * 512 + tx] = (short)f2bf(t[tx][ty + r * 8]);
}

// ------------------------------------------------- QKV projection (128^2 core)
// 1536 blocks 1D. xt 128-row panel (0..127); its 12 consumers co-XCD:
// panel = (s/12)*8 + xcd; t = s%12: t 0-3: kt col-tile t; 4-7: qt; 8-11: vc rows.
__global__ __launch_bounds__(256) void kqv_kernel(
    const short* __restrict__ xt,
    const short* __restrict__ wk, const short* __restrict__ wq, const short* __restrict__ wv,
    const float* __restrict__ bk, const float* __restrict__ bq, const float* __restrict__ bv,
    short* __restrict__ kt, short* __restrict__ qt, short* __restrict__ vc) {
  __shared__ short lds[2 * 128 * 32];
  const int bid = blockIdx.x;
  const int xcd = bid & 7, s = bid >> 3;        // s: 0..191
  const int pg = s / 12, t = s % 12;
  const int panel = pg * 8 + xcd;               // 0..127
  const int z = t >> 2;                         // 0:kt 1:qt 2:vc
  const int ct = t & 3;
  const short *A, *B;
  int arow0, brow0;
  if (z < 2) {
    arow0 = panel * 128; brow0 = ct * 128;
    A = xt + (size_t)arow0 * 512;
    B = ((z == 0) ? wk : wq) + (size_t)brow0 * 512;
  } else {
    arow0 = ct * 128; brow0 = panel * 128;
    A = wv + (size_t)arow0 * 512;
    B = xt + (size_t)brow0 * 512;
  }
  f32x4 acc[4][4] = {};
  gemm_core(A, 512, B, 512, 16, lds, acc);
  const int tid = threadIdx.x, w = tid >> 6, lane = tid & 63;
  const int g = lane >> 4, l15 = lane & 15;
  const int wr = w >> 1, wc = w & 1;
#pragma unroll
  for (int m = 0; m < 4; ++m)
#pragma unroll
    for (int n = 0; n < 4; ++n)
#pragma unroll
      for (int r = 0; r < 4; ++r) {
        int row = wr * 64 + m * 16 + g * 4 + r;
        int col = wc * 64 + n * 16 + l15;
        float v = acc[m][n][r];
        if (z == 0)      kt[(size_t)(arow0 + row) * 512 + brow0 + col] =
                           (short)f2bf((v + bk[brow0 + col]) * QSCALE);
        else if (z == 1) qt[(size_t)(arow0 + row) * 512 + brow0 + col] =
                           (short)f2bf(v + bq[brow0 + col]);
        else             vc[(size_t)(arow0 + row) * 16384 + brow0 + col] =
                           (short)f2bf(v + bv[arow0 + row]);
      }
}

// ------------------------- S-GEMM (128^2 core) + exp2 + row partials -------------------------
// 4096 blocks 1D. xcd = (b,h); s = i(0..31, outer) x j(0..15, inner):
// per i-panel sweep, XCD working set = kt panel 0.25MB + qt 4MB (L2-fit).
__global__ __launch_bounds__(256) void gemm_s_kernel(
    const short* __restrict__ kt, const short* __restrict__ qt,
    short* __restrict__ P, float* __restrict__ Lpart) {
  __shared__ short lds[2 * 128 * 32];
  const int bid = blockIdx.x;
  const int xcd = bid & 7, s = bid >> 3;        // s: 0..511
  const int b = xcd >> 1, h = xcd & 1;
  const int it = s >> 4, jt = s & 15;
  const int i0 = it * 128, jl0 = jt * 128;
  const short* A = kt + ((size_t)((b << 12) + i0)) * 512;
  const short* B = qt + ((size_t)((b << 12) + h * 2048 + jl0)) * 512;
  f32x4 acc[4][4] = {};
  gemm_core(A, 512, B, 512, 16, lds, acc);
  const int tid = threadIdx.x, w = tid >> 6, lane = tid & 63;
  const int g = lane >> 4, l15 = lane & 15;
  const int wr = w >> 1, wc = w & 1;
  short* Pb = P + (size_t)h * 33554432 + ((size_t)((b << 12) + i0)) * 2048 + jl0;
  float psum[4][4];
#pragma unroll
  for (int m = 0; m < 4; ++m)
#pragma unroll
    for (int r = 0; r < 4; ++r) psum[m][r] = 0.f;
#pragma unroll
  for (int m = 0; m < 4; ++m)
#pragma unroll
    for (int n = 0; n < 4; ++n)
#pragma unroll
      for (int r = 0; r < 4; ++r) {
        float p = exp2f(acc[m][n][r]);
        psum[m][r] += p;
        int row = wr * 64 + m * 16 + g * 4 + r;
        int col = wc * 64 + n * 16 + l15;
        Pb[(size_t)row * 2048 + col] = (short)f2bf(p);
      }
  const int jp = (h * 2048 + jl0 + wc * 64) >> 6;
  float* Lp = Lpart + (((size_t)b * 64 + jp) << 12) + i0 + wr * 64;
#pragma unroll
  for (int m = 0; m < 4; ++m)
#pragma unroll
    for (int r = 0; r < 4; ++r) {
      float ss = psum[m][r];
      ss += __shfl_xor(ss, 1); ss += __shfl_xor(ss, 2);
      ss += __shfl_xor(ss, 4); ss += __shfl_xor(ss, 8);
      if (l15 == 0) Lp[m * 16 + g * 4 + r] = ss;
    }
}

// ------------------------------- PV-GEMM (128^2 core, K=2048) -------------------------------
// 1024 blocks 1D. xcd = (b,h); s = i(0..31) x c(0..3).
__global__ __launch_bounds__(256) void gemm_pv_kernel(
    const short* __restrict__ P, const short* __restrict__ vc,
    short* __restrict__ otab) {
  __shared__ short lds[2 * 128 * 32];
  const int bid = blockIdx.x;
  const int xcd = bid & 7, s = bid >> 3;        // s: 0..127
  const int b = xcd >> 1, h = xcd & 1;
  const int it = s >> 2, ct = s & 3;
  const int i0 = it * 128, c0 = ct * 128;
  const short* A = P + (size_t)h * 33554432 + ((size_t)((b << 12) + i0)) * 2048;
  const short* B = vc + (size_t)c0 * 16384 + (b << 12) + h * 2048;
  f32x4 acc[4][4] = {};
  gemm_core(A, 2048, B, 16384, 64, lds, acc);
  const int tid = threadIdx.x, w = tid >> 6, lane = tid & 63;
  const int g = lane >> 4, l15 = lane & 15;
  const int wr = w >> 1, wc = w & 1;
  short* Ob = otab + ((size_t)((b << 12) + i0)) * 1024 + h * 512 + c0;
#pragma unroll
  for (int m = 0; m < 4; ++m)
#pragma unroll
    for (int n = 0; n < 4; ++n)
#pragma unroll
      for (int r = 0; r < 4; ++r) {
        int row = wr * 64 + m * 16 + g * 4 + r;
        int col = wc * 64 + n * 16 + l15;
        Ob[(size_t)row * 1024 + col] = (short)f2bf(acc[m][n][r]);
      }
}

// ------------------------------------------------------------------ l reduce
__global__ __launch_bounds__(256) void lred_kernel(
    const float* __restrict__ Lpart, float* __restrict__ linv) {
  int i = blockIdx.x * 256 + threadIdx.x;      // 16384 = (b,i)
  int b = i >> 12;
  float s = 0.f;
#pragma unroll 8
  for (int jp = 0; jp < 64; ++jp) s += Lpart[(((size_t)b * 64 + jp) << 12) + (i & 4095)];
  linv[i] = 1.0f / s;
}

// ------------------------------ final projection (128^2 core, K=1024) ------------------------------
// 512 blocks 1D. xcd = (b, co-half); s = n-tile(0..31) x co-sub(0..1).
__global__ __launch_bounds__(256) void gemm_out_kernel(
    const short* __restrict__ wdup, const short* __restrict__ otab,
    const float* __restrict__ bo, const float* __restrict__ linv,
    float* __restrict__ out) {
  __shared__ short lds[2 * 128 * 32];
  const int bid = blockIdx.x;
  const int xcd = bid & 7, s = bid >> 3;        // s: 0..63
  const int b = xcd >> 1, ch = xcd & 1;
  const int cot = ch * 2 + (s & 1);
  const int nt = s >> 1;                        // 0..31
  const int arow0 = cot * 128;                  // co
  const int bn0 = nt * 128;                     // n within batch
  const short* A = wdup + (size_t)arow0 * 1024;
  const short* B = otab + ((size_t)((b << 12) + bn0)) * 1024;
  f32x4 acc[4][4] = {};
  gemm_core(A, 1024, B, 1024, 32, lds, acc);
  const int tid = threadIdx.x, w = tid >> 6, lane = tid & 63;
  const int g = lane >> 4, l15 = lane & 15;
  const int wr = w >> 1, wc = w & 1;
#pragma unroll
  for (int m = 0; m < 4; ++m) {
    int co = arow0 + wr * 64 + m * 16 + g * 4;
#pragma unroll
    for (int n = 0; n < 4; ++n) {
      int nl = bn0 + wc * 64 + n * 16 + l15;
      float li = linv[(b << 12) + nl];
#pragma unroll
      for (int r = 0; r < 4; ++r)
        out[((size_t)(b * 512 + co + r) << 12) + nl] = acc[m][n][r] * li + bo[co + r];
    }
  }
}

// ---------------------------------------------------------------------- host
extern "C" void kernel_launch(void* const* d_in, const int* in_sizes, int n_in,
                              void* d_out, int out_size, void* d_ws, size_t ws_size,
                              hipStream_t stream) {
  const float* inp = (const float*)d_in[0];
  const float* Wk = (const float*)d_in[1];
  const float* bk = (const float*)d_in[2];
  const float* Wq = (const float*)d_in[3];
  const float* bq = (const float*)d_in[4];
  const float* Wv = (const float*)d_in[5];
  const float* bv = (const float*)d_in[6];
  const float* Wo = (const float*)d_in[7];
  const float* bo = (const float*)d_in[8];
  float* out = (float*)d_out;
  char* ws = (char*)d_ws;
  const size_t MB = 1048576;
  // layout (227 MB): kt 0..16 | qt 16..32 | vc 32..48 | wb 48..51
  //   xt 51..67 (dead after kqv; Lpart/linv alias) | P 67..195 | otab 195..227
  short* kt    = (short*)(ws);
  short* qt    = (short*)(ws + 16 * MB);
  short* vc    = (short*)(ws + 32 * MB);
  short* wb    = (short*)(ws + 48 * MB);
  short* xt    = (short*)(ws + 51 * MB);
  float* Lpart = (float*)(ws + 51 * MB);
  float* linv  = (float*)(ws + 55 * MB);
  short* P     = (short*)(ws + 67 * MB);
  short* otab  = (short*)(ws + 195 * MB);

  (void)in_sizes; (void)n_in; (void)out_size; (void)ws_size;

  cvt_w_kernel<<<dim3(256, 4), 256, 0, stream>>>(Wk, Wq, Wv, Wo, wb);
  transpose_x_kernel<<<dim3(128, 16, 4), dim3(32, 8, 1), 0, stream>>>(inp, xt);
  kqv_kernel<<<1536, 256, 0, stream>>>(
      xt, wb, wb + 262144, wb + 524288, bk, bq, bv, kt, qt, vc);
  gemm_s_kernel<<<4096, 256, 0, stream>>>(kt, qt, P, Lpart);
  gemm_pv_kernel<<<1024, 256, 0, stream>>>(P, vc, otab);
  lred_kernel<<<64, 256, 0, stream>>>(Lpart, linv);
  gemm_out_kernel<<<512, 256, 0, stream>>>(wb + 786432, otab, bo, linv, out);
}

// Round 10
// 274.669 us; speedup vs baseline: 1.0912x; 1.0912x over previous
//
#include <hip/hip_runtime.h>
#include <hip/hip_bf16.h>

// AttnBlock2D decoupled-GEMM pipeline, R10. B=4, C=512, N=4096 per batch.
//   kt[(b,i)][c] = (x.Wk + bk) * (log2e/sqrt(512))
//   qt[(b,j)][c] = x.Wq + bq
//   vc[c][(b,j)] = x.Wv + bv
//   P_h[b][i][jl] = exp2(kt.qt^T)   (unnormalized), Lpart row partials
//   otab[(b,i)][h*512+c] = P_h.V    (bf16 partial halves side by side)
//   out[b][co][n] = (Wo_dup . otab^T)(K=1024) * linv + bo
// R10: ONE core for all GEMMs — BM=128 x BN=256, BK=64, 4 waves (wave tile
// 128x64 -> 23.4 B/KF LDS traffic, 1.4x less than 64x64), 48KB single-buffer
// LDS with the PROVEN zero-conflict 128B-row/(row&7)<<4 layout, simple
// __syncthreads pacing, 2 blocks/CU co-residency. XCD-aware 1D grids kept.

typedef __attribute__((ext_vector_type(4))) float f32x4;
typedef __attribute__((ext_vector_type(8))) short short8;
typedef __attribute__((ext_vector_type(4))) short short4v;

#define QSCALE 0.06376639774f   // (1/sqrt(512)) * log2(e)

__device__ __forceinline__ unsigned short f2bf(float f) {
  unsigned u = __builtin_bit_cast(unsigned, f);
  unsigned r = (u + 0x7FFFu + ((u >> 16) & 1u)) >> 16;   // RNE
  return (unsigned short)r;
}

__device__ __forceinline__ void gll16(const void* g, void* l) {
  __builtin_amdgcn_global_load_lds((const __attribute__((address_space(1))) void*)g,
                                   (__attribute__((address_space(3))) void*)l, 16, 0, 0);
}

#define MFMA_BF16(d, va, vb) \
  d = __builtin_amdgcn_mfma_f32_16x16x32_bf16(va, vb, d, 0, 0, 0)

// ================= fat-wave 128x256 core (4 waves, BK=64, 48KB LDS) =================
// LDS: A [128 rows][128B] at 0 | B half0 at 16K | B half1 at 32K. Rows 128B,
// 16B-unit XOR swizzle by (row&7)<<4 (zero-conflict, verified R4-R8).
// Wave w owns output cols w*64..w*64+63, all 128 rows. acc[8][4] f32x4 = 128 VGPR.
// Per K-step: sync; 12 gll16 (A + 2 B halves); sync (vmcnt-drained by hipcc);
// 2 k-slices x {8 A-frag + 4 B-frag ds_read_b128, 32 MFMA}.
__device__ __forceinline__ void gemm_fat(
    const short* __restrict__ A, int lda,
    const short* __restrict__ B, int ldb,
    int nkt, char* sm, f32x4 (&acc)[8][4]) {
  const int tid = threadIdx.x, w = tid >> 6, lane = tid & 63;
  const int g = lane >> 4, l15 = lane & 15;
  const int swz = (l15 & 7) << 4;

  for (int t = 0; t < nkt; ++t) {
    __syncthreads();                       // prior slice reads retired
#pragma unroll
    for (int reg = 0; reg < 3; ++reg) {    // 0:A 1:B[0..127] 2:B[128..255]
      const short* src = reg ? B : A;
      const int ld = reg ? ldb : lda;
      const int rbase = (reg == 2) ? 128 : 0;
#pragma unroll
      for (int pass = 0; pass < 4; ++pass) {
        int chunk = pass * 4 + w;
        int o = chunk * 1024 + lane * 16;
        int row = o >> 7;
        int cb = (o & 127) ^ ((row & 7) << 4);
        gll16((const char*)src + (size_t)(rbase + row) * (ld * 2) +
                  (size_t)t * 128 + cb,
              sm + reg * 16384 + chunk * 1024);
      }
    }
    __syncthreads();                       // hipcc drains vmcnt(0) before barrier
#pragma unroll
    for (int ks = 0; ks < 2; ++ks) {
      short8 a[8], bb[4];
#pragma unroll
      for (int i = 0; i < 8; ++i)
        a[i] = *(const short8*)(sm + (i * 16 + l15) * 128 + ((ks * 64 + g * 16) ^ swz));
#pragma unroll
      for (int nf = 0; nf < 4; ++nf) {
        int r = w * 64 + nf * 16 + l15;
        bb[nf] = *(const short8*)(sm + 16384 + (r >> 7) * 16384 + (r & 127) * 128 +
                                  ((ks * 64 + g * 16) ^ swz));
      }
      __builtin_amdgcn_s_setprio(1);
#pragma unroll
      for (int i = 0; i < 8; ++i)
#pragma unroll
        for (int nf = 0; nf < 4; ++nf)
          MFMA_BF16(acc[i][nf], a[i], bb[nf]);
      __builtin_amdgcn_s_setprio(0);
    }
  }
}

// ---------------------------------------------------------------- cvt weights
__global__ __launch_bounds__(256) void cvt_w_kernel(
    const float* __restrict__ wk, const float* __restrict__ wq,
    const float* __restrict__ wv, const float* __restrict__ wo,
    short* __restrict__ o) {
  int z = blockIdx.y;
  const float* s = (z == 0) ? wk : (z == 1) ? wq : (z == 2) ? wv : wo;
  int i = blockIdx.x * 256 + threadIdx.x;
  float4 f = ((const float4*)s)[i];
  short4v v;
  v[0] = (short)f2bf(f.x); v[1] = (short)f2bf(f.y);
  v[2] = (short)f2bf(f.z); v[3] = (short)f2bf(f.w);
  if (z < 3) {
    *(short4v*)(o + z * 262144 + i * 4) = v;
  } else {                       // Wo duplicated along K: wdup[co][1024]
    int idx = i * 4, co = idx >> 9, cc = idx & 511;
    short* base = o + 786432 + co * 1024 + cc;
    *(short4v*)base = v;
    *(short4v*)(base + 512) = v;
  }
}

// --------------------------------------------------- transpose inp -> x_t bf16
__global__ __launch_bounds__(256) void transpose_x_kernel(
    const float* __restrict__ inp, short* __restrict__ xt) {
  __shared__ float t[32][33];
  int tx = threadIdx.x, ty = threadIdx.y;
  int n0 = blockIdx.x * 32, c0 = blockIdx.y * 32, b = blockIdx.z;
  const float* src = inp + ((size_t)(b * 512 + c0)) * 4096 + n0;
#pragma unroll
  for (int r = 0; r < 4; ++r) t[ty + r * 8][tx] = src[(ty + r * 8) * 4096 + tx];
  __syncthreads();
  short* dst = xt + ((size_t)((b << 12) + n0)) * 512 + c0;
#pragma unroll
  for (int r = 0; r < 4; ++r) dst[(ty + r * 8) * 512 + tx] = (short)f2bf(t[tx][ty + r * 8]);
}

// ------------------------------------------------- QKV projection (fat core)
// 768 blocks 1D. xt 256-row group gg (0..63) -> xcd gg&7; its 12 consumer
// blocks co-XCD. t: 0-3 kt (nsub=t>>1, ct=t&1), 4-7 qt, 8-11 vc (ct=t-8).
__global__ __launch_bounds__(256, 2) void kqv_kernel(
    const short* __restrict__ xt,
    const short* __restrict__ wk, const short* __restrict__ wq, const short* __restrict__ wv,
    const float* __restrict__ bk, const float* __restrict__ bq, const float* __restrict__ bv,
    short* __restrict__ kt, short* __restrict__ qt, short* __restrict__ vc) {
  __shared__ char sm[49152];
  const int bid = blockIdx.x;
  const int xcd = bid & 7, s = bid >> 3;        // s: 0..95
  const int gg = (s / 12) * 8 + xcd;            // 0..63
  const int t = s % 12;
  const int z = (t < 8) ? (t >> 2) : 2;
  const short *A, *B;
  int arow0, brow0;
  if (z < 2) {
    arow0 = gg * 256 + ((t >> 1) & 1) * 128;    // n rows (128)
    brow0 = (t & 1) * 256;                      // c cols (256)
    A = xt + (size_t)arow0 * 512;
    B = ((z == 0) ? wk : wq) + (size_t)brow0 * 512;
  } else {
    arow0 = (t - 8) * 128;                      // c rows (128)
    brow0 = gg * 256;                           // n cols (256)
    A = wv + (size_t)arow0 * 512;
    B = xt + (size_t)brow0 * 512;
  }
  f32x4 acc[8][4] = {};
  gemm_fat(A, 512, B, 512, 8, sm, acc);
  const int tid = threadIdx.x, w = tid >> 6, lane = tid & 63;
  const int gq = lane >> 4, l15 = lane & 15;
#pragma unroll
  for (int mf = 0; mf < 8; ++mf)
#pragma unroll
    for (int nf = 0; nf < 4; ++nf)
#pragma unroll
      for (int r = 0; r < 4; ++r) {
        int row = mf * 16 + gq * 4 + r;
        int col = w * 64 + nf * 16 + l15;
        float v = acc[mf][nf][r];
        if (z == 0)      kt[(size_t)(arow0 + row) * 512 + brow0 + col] =
                           (short)f2bf((v + bk[brow0 + col]) * QSCALE);
        else if (z == 1) qt[(size_t)(arow0 + row) * 512 + brow0 + col] =
                           (short)f2bf(v + bq[brow0 + col]);
        else             vc[(size_t)(arow0 + row) * 16384 + brow0 + col] =
                           (short)f2bf(v + bv[arow0 + row]);
      }
}

// ------------------------- S-GEMM (fat core) + exp2 + row partials -------------------------
// 2048 blocks 1D. xcd = (b,h); s = it(0..31, outer) x jt(0..7): per i-panel
// round, XCD set = kt 128KB + qt 2MB (L2-fit).
__global__ __launch_bounds__(256, 2) void gemm_s_kernel(
    const short* __restrict__ kt, const short* __restrict__ qt,
    short* __restrict__ P, float* __restrict__ Lpart) {
  __shared__ char sm[49152];
  const int bid = blockIdx.x;
  const int xcd = bid & 7, s = bid >> 3;        // s: 0..255
  const int b = xcd >> 1, h = xcd & 1;
  const int it = s >> 3, jt = s & 7;
  const int i0 = it * 128, jt0 = jt * 256;
  const short* A = kt + ((size_t)((b << 12) + i0)) * 512;
  const short* B = qt + ((size_t)((b << 12) + h * 2048 + jt0)) * 512;
  f32x4 acc[8][4] = {};
  gemm_fat(A, 512, B, 512, 8, sm, acc);
  const int tid = threadIdx.x, w = tid >> 6, lane = tid & 63;
  const int gq = lane >> 4, l15 = lane & 15;
  short* Pb = P + (size_t)h * 33554432 + ((size_t)((b << 12) + i0)) * 2048 + jt0;
  float psum[8][4];
#pragma unroll
  for (int mf = 0; mf < 8; ++mf)
#pragma unroll
    for (int r = 0; r < 4; ++r) psum[mf][r] = 0.f;
#pragma unroll
  for (int mf = 0; mf < 8; ++mf)
#pragma unroll
    for (int nf = 0; nf < 4; ++nf)
#pragma unroll
      for (int r = 0; r < 4; ++r) {
        float p = exp2f(acc[mf][nf][r]);
        psum[mf][r] += p;
        int row = mf * 16 + gq * 4 + r;
        int col = w * 64 + nf * 16 + l15;
        Pb[(size_t)row * 2048 + col] = (short)f2bf(p);
      }
  const int jp = (h * 2048 + jt0 + w * 64) >> 6;    // per-wave 64-col slot
  float* Lp = Lpart + (((size_t)b * 64 + jp) << 12) + i0;
#pragma unroll
  for (int mf = 0; mf < 8; ++mf)
#pragma unroll
    for (int r = 0; r < 4; ++r) {
      float ss = psum[mf][r];
      ss += __shfl_xor(ss, 1); ss += __shfl_xor(ss, 2);
      ss += __shfl_xor(ss, 4); ss += __shfl_xor(ss, 8);
      if (l15 == 0) Lp[mf * 16 + gq * 4 + r] = ss;
    }
}

// ------------------------------- PV-GEMM (fat core, K=2048) -------------------------------
// 512 blocks 1D. xcd = (b,h); s = it(0..31) x ct(0..1).
__global__ __launch_bounds__(256, 2) void gemm_pv_kernel(
    const short* __restrict__ P, const short* __restrict__ vc,
    short* __restrict__ otab) {
  __shared__ char sm[49152];
  const int bid = blockIdx.x;
  const int xcd = bid & 7, s = bid >> 3;        // s: 0..63
  const int b = xcd >> 1, h = xcd & 1;
  const int it = s >> 1, ct = s & 1;
  const int i0 = it * 128, c0 = ct * 256;
  const short* A = P + (size_t)h * 33554432 + ((size_t)((b << 12) + i0)) * 2048;
  const short* B = vc + (size_t)c0 * 16384 + (b << 12) + h * 2048;
  f32x4 acc[8][4] = {};
  gemm_fat(A, 2048, B, 16384, 32, sm, acc);
  const int tid = threadIdx.x, w = tid >> 6, lane = tid & 63;
  const int gq = lane >> 4, l15 = lane & 15;
  short* Ob = otab + ((size_t)((b << 12) + i0)) * 1024 + h * 512 + c0;
#pragma unroll
  for (int mf = 0; mf < 8; ++mf)
#pragma unroll
    for (int nf = 0; nf < 4; ++nf)
#pragma unroll
      for (int r = 0; r < 4; ++r) {
        int row = mf * 16 + gq * 4 + r;
        int col = w * 64 + nf * 16 + l15;
        Ob[(size_t)row * 1024 + col] = (short)f2bf(acc[mf][nf][r]);
      }
}

// ------------------------------------------------------------------ l reduce
__global__ __launch_bounds__(256) void lred_kernel(
    const float* __restrict__ Lpart, float* __restrict__ linv) {
  int i = blockIdx.x * 256 + threadIdx.x;      // 16384 = (b,i)
  int b = i >> 12;
  float s = 0.f;
#pragma unroll 8
  for (int jp = 0; jp < 64; ++jp) s += Lpart[(((size_t)b * 64 + jp) << 12) + (i & 4095)];
  linv[i] = 1.0f / s;
}

// ------------------------------ final projection (fat core, K=1024) ------------------------------
// 256 blocks 1D. xcd = (b, co-half); s = nt(0..15) x co-sub(0..1).
__global__ __launch_bounds__(256, 2) void gemm_out_kernel(
    const short* __restrict__ wdup, const short* __restrict__ otab,
    const float* __restrict__ bo, const float* __restrict__ linv,
    float* __restrict__ out) {
  __shared__ char sm[49152];
  const int bid = blockIdx.x;
  const int xcd = bid & 7, s = bid >> 3;        // s: 0..31
  const int b = xcd >> 1, ch = xcd & 1;
  const int cot = ch * 2 + (s & 1);             // 0..3
  const int nt = s >> 1;                        // 0..15
  const int arow0 = cot * 128;                  // co
  const int bn0 = nt * 256;                     // n within batch
  const short* A = wdup + (size_t)arow0 * 1024;
  const short* B = otab + ((size_t)((b << 12) + bn0)) * 1024;
  f32x4 acc[8][4] = {};
  gemm_fat(A, 1024, B, 1024, 16, sm, acc);
  const int tid = threadIdx.x, w = tid >> 6, lane = tid & 63;
  const int gq = lane >> 4, l15 = lane & 15;
#pragma unroll
  for (int mf = 0; mf < 8; ++mf) {
    int co = arow0 + mf * 16 + gq * 4;
#pragma unroll
    for (int nf = 0; nf < 4; ++nf) {
      int nl = bn0 + w * 64 + nf * 16 + l15;
      float li = linv[(b << 12) + nl];
#pragma unroll
      for (int r = 0; r < 4; ++r)
        out[((size_t)(b * 512 + co + r) << 12) + nl] = acc[mf][nf][r] * li + bo[co + r];
    }
  }
}

// ---------------------------------------------------------------------- host
extern "C" void kernel_launch(void* const* d_in, const int* in_sizes, int n_in,
                              void* d_out, int out_size, void* d_ws, size_t ws_size,
                              hipStream_t stream) {
  const float* inp = (const float*)d_in[0];
  const float* Wk = (const float*)d_in[1];
  const float* bk = (const float*)d_in[2];
  const float* Wq = (const float*)d_in[3];
  const float* bq = (const float*)d_in[4];
  const float* Wv = (const float*)d_in[5];
  const float* bv = (const float*)d_in[6];
  const float* Wo = (const float*)d_in[7];
  const float* bo = (const float*)d_in[8];
  float* out = (float*)d_out;
  char* ws = (char*)d_ws;
  const size_t MB = 1048576;
  // layout (227 MB): kt 0..16 | qt 16..32 | vc 32..48 | wb 48..51
  //   xt 51..67 (dead after kqv; Lpart/linv alias) | P 67..195 | otab 195..227
  short* kt    = (short*)(ws);
  short* qt    = (short*)(ws + 16 * MB);
  short* vc    = (short*)(ws + 32 * MB);
  short* wb    = (short*)(ws + 48 * MB);
  short* xt    = (short*)(ws + 51 * MB);
  float* Lpart = (float*)(ws + 51 * MB);
  float* linv  = (float*)(ws + 55 * MB);
  short* P     = (short*)(ws + 67 * MB);
  short* otab  = (short*)(ws + 195 * MB);

  (void)in_sizes; (void)n_in; (void)out_size; (void)ws_size;

  cvt_w_kernel<<<dim3(256, 4), 256, 0, stream>>>(Wk, Wq, Wv, Wo, wb);
  transpose_x_kernel<<<dim3(128, 16, 4), dim3(32, 8, 1), 0, stream>>>(inp, xt);
  kqv_kernel<<<768, 256, 0, stream>>>(
      xt, wb, wb + 262144, wb + 524288, bk, bq, bv, kt, qt, vc);
  gemm_s_kernel<<<2048, 256, 0, stream>>>(kt, qt, P, Lpart);
  gemm_pv_kernel<<<512, 256, 0, stream>>>(P, vc, otab);
  lred_kernel<<<64, 256, 0, stream>>>(Lpart, linv);
  gemm_out_kernel<<<256, 256, 0, stream>>>(wb + 786432, otab, bo, linv, out);
}

// Round 13
// 266.804 us; speedup vs baseline: 1.1234x; 1.0295x over previous
//
#include <hip/hip_runtime.h>
#include <hip/hip_bf16.h>

// AttnBlock2D decoupled-GEMM pipeline, R13. B=4, C=512, N=4096 per batch.
//   kth[(b,i)][c] = x.Wk + bk   (fp16, staged in P region)
//   qth[(b,j)][c] = x.Wq + bq   (fp16)
//   PER-ROW int8 quant: kt8 = round(127/rowmax * kth), sk[i] = rowmax*sqrt(QS)/127
//   (same for qt8/sq). No clipping ever; step ~0.42x of R11's global-scale.
//   vc[c][(b,j)] = x.Wv + bv    (fp16 channel-major)
//   P_h[b][i][jl] = exp2(acc_i32 * sk_i * sq_j - 4)   (fp16, unnormalized;
//                   row scale cancels in O/l)
//   otab[(b,i)][h*512+c] = P_h.V  (fp16 halves side by side)
//   out[b][co][n] = (Wo_dup . otab^T)(K=1024) * linv + bo
// Structure/grids = R10 (fat 128x256 core, XCD-aware 1D grids, verified).

typedef __attribute__((ext_vector_type(4))) float f32x4;
typedef __attribute__((ext_vector_type(4))) int i32x4;
typedef _Float16 half8 __attribute__((ext_vector_type(8)));
typedef __attribute__((ext_vector_type(4))) short short4v;
typedef __attribute__((ext_vector_type(8))) signed char schar8;

// sqrt(QSCALE) where QSCALE = log2(e)/sqrt(512) = 0.063766398
#define SQRT_QS 0.2525200f

__device__ __forceinline__ unsigned short f2h(float f) {
  _Float16 h = (_Float16)f;                    // v_cvt_f16_f32 (RNE)
  return __builtin_bit_cast(unsigned short, h);
}

__device__ __forceinline__ void gll16(const void* g, void* l) {
  __builtin_amdgcn_global_load_lds((const __attribute__((address_space(1))) void*)g,
                                   (__attribute__((address_space(3))) void*)l, 16, 0, 0);
}

#define MFMA_F16(d, va, vb) \
  d = __builtin_amdgcn_mfma_f32_16x16x32_f16(va, vb, d, 0, 0, 0)
#define MFMA_I8(d, va, vb) \
  d = __builtin_amdgcn_mfma_i32_16x16x64_i8(va, vb, d, 0, 0, 0)

// ================= fat-wave 128x256 fp16 core (4 waves, BK=64, 48KB LDS) =================
// LDS: A [128 rows][128B] | B half0 | B half1 (16KB each). (row&7)<<4 XOR swizzle.
__device__ __forceinline__ void gemm_fat(
    const short* __restrict__ A, int lda,
    const short* __restrict__ B, int ldb,
    int nkt, char* sm, f32x4 (&acc)[8][4]) {
  const int tid = threadIdx.x, w = tid >> 6, lane = tid & 63;
  const int g = lane >> 4, l15 = lane & 15;
  const int swz = (l15 & 7) << 4;

  for (int t = 0; t < nkt; ++t) {
    __syncthreads();
#pragma unroll
    for (int reg = 0; reg < 3; ++reg) {
      const short* src = reg ? B : A;
      const int ld = reg ? ldb : lda;
      const int rbase = (reg == 2) ? 128 : 0;
#pragma unroll
      for (int pass = 0; pass < 4; ++pass) {
        int chunk = pass * 4 + w;
        int o = chunk * 1024 + lane * 16;
        int row = o >> 7;
        int cb = (o & 127) ^ ((row & 7) << 4);
        gll16((const char*)src + (size_t)(rbase + row) * (ld * 2) +
                  (size_t)t * 128 + cb,
              sm + reg * 16384 + chunk * 1024);
      }
    }
    __syncthreads();
#pragma unroll
    for (int ks = 0; ks < 2; ++ks) {
      half8 a[8], bb[4];
#pragma unroll
      for (int i = 0; i < 8; ++i)
        a[i] = *(const half8*)(sm + (i * 16 + l15) * 128 + ((ks * 64 + g * 16) ^ swz));
#pragma unroll
      for (int nf = 0; nf < 4; ++nf) {
        int r = w * 64 + nf * 16 + l15;
        bb[nf] = *(const half8*)(sm + 16384 + (r >> 7) * 16384 + (r & 127) * 128 +
                                 ((ks * 64 + g * 16) ^ swz));
      }
      __builtin_amdgcn_s_setprio(1);
#pragma unroll
      for (int i = 0; i < 8; ++i)
#pragma unroll
        for (int nf = 0; nf < 4; ++nf)
          MFMA_F16(acc[i][nf], a[i], bb[nf]);
      __builtin_amdgcn_s_setprio(0);
    }
  }
}

// ================= fat-wave 128x256 INT8 core (BK=128, byte-identical LDS) =================
__device__ __forceinline__ void gemm_fat_i8(
    const signed char* __restrict__ A, int ldaB,
    const signed char* __restrict__ B, int ldbB,
    int nkt, char* sm, i32x4 (&acc)[8][4]) {
  const int tid = threadIdx.x, w = tid >> 6, lane = tid & 63;
  const int g = lane >> 4, l15 = lane & 15;
  const int swz = (l15 & 7) << 4;

  for (int t = 0; t < nkt; ++t) {
    __syncthreads();
#pragma unroll
    for (int reg = 0; reg < 3; ++reg) {
      const signed char* src = reg ? B : A;
      const int ld = reg ? ldbB : ldaB;
      const int rbase = (reg == 2) ? 128 : 0;
#pragma unroll
      for (int pass = 0; pass < 4; ++pass) {
        int chunk = pass * 4 + w;
        int o = chunk * 1024 + lane * 16;
        int row = o >> 7;
        int cb = (o & 127) ^ ((row & 7) << 4);
        gll16((const char*)src + (size_t)(rbase + row) * ld + (size_t)t * 128 + cb,
              sm + reg * 16384 + chunk * 1024);
      }
    }
    __syncthreads();
#pragma unroll
    for (int ks = 0; ks < 2; ++ks) {
      i32x4 a[8], bb[4];
#pragma unroll
      for (int i = 0; i < 8; ++i)
        a[i] = *(const i32x4*)(sm + (i * 16 + l15) * 128 + ((ks * 64 + g * 16) ^ swz));
#pragma unroll
      for (int nf = 0; nf < 4; ++nf) {
        int r = w * 64 + nf * 16 + l15;
        bb[nf] = *(const i32x4*)(sm + 16384 + (r >> 7) * 16384 + (r & 127) * 128 +
                                 ((ks * 64 + g * 16) ^ swz));
      }
      __builtin_amdgcn_s_setprio(1);
#pragma unroll
      for (int i = 0; i < 8; ++i)
#pragma unroll
        for (int nf = 0; nf < 4; ++nf)
          MFMA_I8(acc[i][nf], a[i], bb[nf]);
      __builtin_amdgcn_s_setprio(0);
    }
  }
}

// ---------------------------------------------------------------- cvt weights (fp16)
__global__ __launch_bounds__(256) void cvt_w_kernel(
    const float* __restrict__ wk, const float* __restrict__ wq,
    const float* __restrict__ wv, const float* __restrict__ wo,
    short* __restrict__ o) {
  int z = blockIdx.y;
  const float* s = (z == 0) ? wk : (z == 1) ? wq : (z == 2) ? wv : wo;
  int i = blockIdx.x * 256 + threadIdx.x;
  float4 f = ((const float4*)s)[i];
  short4v v;
  v[0] = (short)f2h(f.x); v[1] = (short)f2h(f.y);
  v[2] = (short)f2h(f.z); v[3] = (short)f2h(f.w);
  if (z < 3) {
    *(short4v*)(o + z * 262144 + i * 4) = v;
  } else {                       // Wo duplicated along K: wdup[co][1024]
    int idx = i * 4, co = idx >> 9, cc = idx & 511;
    short* base = o + 786432 + co * 1024 + cc;
    *(short4v*)base = v;
    *(short4v*)(base + 512) = v;
  }
}

// --------------------------------------------------- transpose inp -> x_t fp16
__global__ __launch_bounds__(256) void transpose_x_kernel(
    const float* __restrict__ inp, short* __restrict__ xt) {
  __shared__ float t[32][33];
  int tx = threadIdx.x, ty = threadIdx.y;
  int n0 = blockIdx.x * 32, c0 = blockIdx.y * 32, b = blockIdx.z;
  const float* src = inp + ((size_t)(b * 512 + c0)) * 4096 + n0;
#pragma unroll
  for (int r = 0; r < 4; ++r) t[ty + r * 8][tx] = src[(ty + r * 8) * 4096 + tx];
  __syncthreads();
  short* dst = xt + ((size_t)((b << 12) + n0)) * 512 + c0;
#pragma unroll
  for (int r = 0; r < 4; ++r) dst[(ty + r * 8) * 512 + tx] = (short)f2h(t[tx][ty + r * 8]);
}

// ------------------------------------------------- QKV projection (fp16 fat core)
// 768 blocks 1D (R10 mapping). z=0/1 -> fp16 kth/qth (raw + bias); z=2 -> vc fp16.
__global__ __launch_bounds__(256, 2) void kqv_kernel(
    const short* __restrict__ xt,
    const short* __restrict__ wk, const short* __restrict__ wq, const short* __restrict__ wv,
    const float* __restrict__ bk, const float* __restrict__ bq, const float* __restrict__ bv,
    short* __restrict__ kth, short* __restrict__ qth,
    short* __restrict__ vc) {
  __shared__ char sm[49152];
  const int bid = blockIdx.x;
  const int xcd = bid & 7, s = bid >> 3;        // s: 0..95
  const int gg = (s / 12) * 8 + xcd;            // 0..63
  const int t = s % 12;
  const int z = (t < 8) ? (t >> 2) : 2;
  const short *A, *B;
  int arow0, brow0;
  if (z < 2) {
    arow0 = gg * 256 + ((t >> 1) & 1) * 128;    // n rows (128)
    brow0 = (t & 1) * 256;                      // c cols (256)
    A = xt + (size_t)arow0 * 512;
    B = ((z == 0) ? wk : wq) + (size_t)brow0 * 512;
  } else {
    arow0 = (t - 8) * 128;                      // c rows (128)
    brow0 = gg * 256;                           // n cols (256)
    A = wv + (size_t)arow0 * 512;
    B = xt + (size_t)brow0 * 512;
  }
  f32x4 acc[8][4] = {};
  gemm_fat(A, 512, B, 512, 8, sm, acc);
  const int tid = threadIdx.x, w = tid >> 6, lane = tid & 63;
  const int gq = lane >> 4, l15 = lane & 15;
#pragma unroll
  for (int mf = 0; mf < 8; ++mf)
#pragma unroll
    for (int nf = 0; nf < 4; ++nf)
#pragma unroll
      for (int r = 0; r < 4; ++r) {
        int row = mf * 16 + gq * 4 + r;
        int col = w * 64 + nf * 16 + l15;
        float v = acc[mf][nf][r];
        if (z == 2) {
          vc[(size_t)(arow0 + row) * 16384 + brow0 + col] =
              (short)f2h(v + bv[arow0 + row]);
        } else {
          short* dst = (z == 0) ? kth : qth;
          float bias = (z == 0) ? bk[brow0 + col] : bq[brow0 + col];
          dst[(size_t)(arow0 + row) * 512 + brow0 + col] = (short)f2h(v + bias);
        }
      }
}

// ---------------------- per-row int8 quantization (k and q, 32768 rows) ----------------------
// One wave per row: wave-max via shfl_xor, scale 127/rowmax (no clipping),
// scl[row] = rowmax * sqrt(QSCALE)/127 so exp2 arg = acc * sk_i * sq_j.
__global__ __launch_bounds__(256) void quant_kernel(
    const short* __restrict__ src, signed char* __restrict__ dst,
    float* __restrict__ scl) {
  const int row = blockIdx.x * 4 + (threadIdx.x >> 6);
  const int lane = threadIdx.x & 63;
  half8 v = *(const half8*)(src + (size_t)row * 512 + lane * 8);
  float f[8];
  float m = 0.f;
#pragma unroll
  for (int e = 0; e < 8; ++e) { f[e] = (float)v[e]; m = fmaxf(m, fabsf(f[e])); }
#pragma unroll
  for (int off = 1; off < 64; off <<= 1) m = fmaxf(m, __shfl_xor(m, off));
  m = fmaxf(m, 1e-6f);
  const float inv = 127.0f / m;
  schar8 q;
#pragma unroll
  for (int e = 0; e < 8; ++e) q[e] = (signed char)(int)rintf(f[e] * inv);
  *(schar8*)(dst + (size_t)row * 512 + lane * 8) = q;
  if (lane == 0) scl[row] = m * (SQRT_QS / 127.0f);
}

// ------------------------- S-GEMM (i8 fat core) + exp2 + row partials -------------------------
// 2048 blocks 1D (R10 mapping). K=512 i8 -> 4 K-steps of 128.
// P stored fp16 pre-scaled 2^-4 (cancels in O/l); per-row scales sk/sq applied here.
__global__ __launch_bounds__(256, 2) void gemm_s_kernel(
    const signed char* __restrict__ kt8, const signed char* __restrict__ qt8,
    const float* __restrict__ sk, const float* __restrict__ sq,
    short* __restrict__ P, float* __restrict__ Lpart) {
  __shared__ char sm[49152];
  const int bid = blockIdx.x;
  const int xcd = bid & 7, s = bid >> 3;        // s: 0..255
  const int b = xcd >> 1, h = xcd & 1;
  const int it = s >> 3, jt = s & 7;
  const int i0 = it * 128, jt0 = jt * 256;
  const signed char* A = kt8 + ((size_t)((b << 12) + i0)) * 512;
  const signed char* B = qt8 + ((size_t)((b << 12) + h * 2048 + jt0)) * 512;
  i32x4 acc[8][4] = {};
  gemm_fat_i8(A, 512, B, 512, 4, sm, acc);
  const int tid = threadIdx.x, w = tid >> 6, lane = tid & 63;
  const int gq = lane >> 4, l15 = lane & 15;
  const float* skp = sk + (b << 12) + i0;
  const float* sqp = sq + (b << 12) + h * 2048 + jt0;
  float sqc[4];
#pragma unroll
  for (int nf = 0; nf < 4; ++nf) sqc[nf] = sqp[w * 64 + nf * 16 + l15];
  short* Pb = P + (size_t)h * 33554432 + ((size_t)((b << 12) + i0)) * 2048 + jt0;
  float psum[8][4];
#pragma unroll
  for (int mf = 0; mf < 8; ++mf)
#pragma unroll
    for (int r = 0; r < 4; ++r) psum[mf][r] = 0.f;
#pragma unroll
  for (int mf = 0; mf < 8; ++mf) {
    float skr[4];
#pragma unroll
    for (int r = 0; r < 4; ++r) skr[r] = skp[mf * 16 + gq * 4 + r];
#pragma unroll
    for (int nf = 0; nf < 4; ++nf)
#pragma unroll
      for (int r = 0; r < 4; ++r) {
        float p = exp2f((float)acc[mf][nf][r] * skr[r] * sqc[nf] - 4.0f);
        psum[mf][r] += p;
        int row = mf * 16 + gq * 4 + r;
        int col = w * 64 + nf * 16 + l15;
        Pb[(size_t)row * 2048 + col] = (short)f2h(p);
      }
  }
  const int jp = (h * 2048 + jt0 + w * 64) >> 6;    // per-wave 64-col slot
  float* Lp = Lpart + (((size_t)b * 64 + jp) << 12) + i0;
#pragma unroll
  for (int mf = 0; mf < 8; ++mf)
#pragma unroll
    for (int r = 0; r < 4; ++r) {
      float ss = psum[mf][r];
      ss += __shfl_xor(ss, 1); ss += __shfl_xor(ss, 2);
      ss += __shfl_xor(ss, 4); ss += __shfl_xor(ss, 8);
      if (l15 == 0) Lp[mf * 16 + gq * 4 + r] = ss;
    }
}

// ------------------------------- PV-GEMM (fp16 fat core, K=2048) -------------------------------
// 512 blocks 1D (R10 mapping).
__global__ __launch_bounds__(256, 2) void gemm_pv_kernel(
    const short* __restrict__ P, const short* __restrict__ vc,
    short* __restrict__ otab) {
  __shared__ char sm[49152];
  const int bid = blockIdx.x;
  const int xcd = bid & 7, s = bid >> 3;        // s: 0..63
  const int b = xcd >> 1, h = xcd & 1;
  const int it = s >> 1, ct = s & 1;
  const int i0 = it * 128, c0 = ct * 256;
  const short* A = P + (size_t)h * 33554432 + ((size_t)((b << 12) + i0)) * 2048;
  const short* B = vc + (size_t)c0 * 16384 + (b << 12) + h * 2048;
  f32x4 acc[8][4] = {};
  gemm_fat(A, 2048, B, 16384, 32, sm, acc);
  const int tid = threadIdx.x, w = tid >> 6, lane = tid & 63;
  const int gq = lane >> 4, l15 = lane & 15;
  short* Ob = otab + ((size_t)((b << 12) + i0)) * 1024 + h * 512 + c0;
#pragma unroll
  for (int mf = 0; mf < 8; ++mf)
#pragma unroll
    for (int nf = 0; nf < 4; ++nf)
#pragma unroll
      for (int r = 0; r < 4; ++r) {
        int row = mf * 16 + gq * 4 + r;
        int col = w * 64 + nf * 16 + l15;
        Ob[(size_t)row * 1024 + col] = (short)f2h(acc[mf][nf][r]);
      }
}

// ------------------------------------------------------------------ l reduce
__global__ __launch_bounds__(256) void lred_kernel(
    const float* __restrict__ Lpart, float* __restrict__ linv) {
  int i = blockIdx.x * 256 + threadIdx.x;      // 16384 = (b,i)
  int b = i >> 12;
  float s = 0.f;
#pragma unroll 8
  for (int jp = 0; jp < 64; ++jp) s += Lpart[(((size_t)b * 64 + jp) << 12) + (i & 4095)];
  linv[i] = 1.0f / s;
}

// ------------------------------ final projection (fp16 fat core, K=1024) ------------------------------
// 256 blocks 1D (R10 mapping).
__global__ __launch_bounds__(256, 2) void gemm_out_kernel(
    const short* __restrict__ wdup, const short* __restrict__ otab,
    const float* __restrict__ bo, const float* __restrict__ linv,
    float* __restrict__ out) {
  __shared__ char sm[49152];
  const int bid = blockIdx.x;
  const int xcd = bid & 7, s = bid >> 3;        // s: 0..31
  const int b = xcd >> 1, ch = xcd & 1;
  const int cot = ch * 2 + (s & 1);             // 0..3
  const int nt = s >> 1;                        // 0..15
  const int arow0 = cot * 128;                  // co
  const int bn0 = nt * 256;                     // n within batch
  const short* A = wdup + (size_t)arow0 * 1024;
  const short* B = otab + ((size_t)((b << 12) + bn0)) * 1024;
  f32x4 acc[8][4] = {};
  gemm_fat(A, 1024, B, 1024, 16, sm, acc);
  const int tid = threadIdx.x, w = tid >> 6, lane = tid & 63;
  const int gq = lane >> 4, l15 = lane & 15;
#pragma unroll
  for (int mf = 0; mf < 8; ++mf) {
    int co = arow0 + mf * 16 + gq * 4;
#pragma unroll
    for (int nf = 0; nf < 4; ++nf) {
      int nl = bn0 + w * 64 + nf * 16 + l15;
      float li = linv[(b << 12) + nl];
#pragma unroll
      for (int r = 0; r < 4; ++r)
        out[((size_t)(b * 512 + co + r) << 12) + nl] = acc[mf][nf][r] * li + bo[co + r];
    }
  }
}

// ---------------------------------------------------------------------- host
extern "C" void kernel_launch(void* const* d_in, const int* in_sizes, int n_in,
                              void* d_out, int out_size, void* d_ws, size_t ws_size,
                              hipStream_t stream) {
  const float* inp = (const float*)d_in[0];
  const float* Wk = (const float*)d_in[1];
  const float* bk = (const float*)d_in[2];
  const float* Wq = (const float*)d_in[3];
  const float* bq = (const float*)d_in[4];
  const float* Wv = (const float*)d_in[5];
  const float* bv = (const float*)d_in[6];
  const float* Wo = (const float*)d_in[7];
  const float* bo = (const float*)d_in[8];
  float* out = (float*)d_out;
  char* ws = (char*)d_ws;
  const size_t MB = 1048576;
  // layout (227 MB): kt8 0..8 | qt8 8..16 | sk/sq 16..16.125 | vc 32..48 |
  //   wb 48..51 | xt 51..67 (dead after kqv; Lpart/linv alias) |
  //   P 67..195 (kth 67..83, qth 83..99 live only kqv->quant) | otab 195..227
  signed char* kt8 = (signed char*)(ws);
  signed char* qt8 = (signed char*)(ws + 8 * MB);
  float* sk    = (float*)(ws + 16 * MB);          // sq = sk + 16384
  short* vc    = (short*)(ws + 32 * MB);
  short* wb    = (short*)(ws + 48 * MB);
  short* xt    = (short*)(ws + 51 * MB);
  float* Lpart = (float*)(ws + 51 * MB);
  float* linv  = (float*)(ws + 55 * MB);
  short* P     = (short*)(ws + 67 * MB);
  short* kth   = (short*)(ws + 67 * MB);          // aliases P (consumed pre-S)
  short* qth   = (short*)(ws + 83 * MB);
  short* otab  = (short*)(ws + 195 * MB);

  (void)in_sizes; (void)n_in; (void)out_size; (void)ws_size;

  cvt_w_kernel<<<dim3(256, 4), 256, 0, stream>>>(Wk, Wq, Wv, Wo, wb);
  transpose_x_kernel<<<dim3(128, 16, 4), dim3(32, 8, 1), 0, stream>>>(inp, xt);
  kqv_kernel<<<768, 256, 0, stream>>>(
      xt, wb, wb + 262144, wb + 524288, bk, bq, bv, kth, qth, vc);
  quant_kernel<<<8192, 256, 0, stream>>>(kth, kt8, sk);   // kth/qth, kt8/qt8,
  gemm_s_kernel<<<2048, 256, 0, stream>>>(                //   sk/sq contiguous
      kt8, qt8, sk, sk + 16384, P, Lpart);
  gemm_pv_kernel<<<512, 256, 0, stream>>>(P, vc, otab);
  lred_kernel<<<64, 256, 0, stream>>>(Lpart, linv);
  gemm_out_kernel<<<256, 256, 0, stream>>>(wb + 786432, otab, bo, linv, out);
}